// Round 6
// baseline (200.855 us; speedup 1.0000x reference)
//
#include <hip/hip_runtime.h>
#include <hip/hip_cooperative_groups.h>
#include <math.h>

namespace cg = cooperative_groups;

#define NBATCH 128
#define S 7
#define NCLS 20
#define CH 30
#define N 12544              // 128*7*7*2
#define PERB 98              // boxes per batch
#define NWORDS 196           // N/64 ballot words
#define NBLK 49              // N/256 decode blocks
#define NCHUNK 16            // rank column chunks
#define CLENMAX 784          // ceil(N/NCHUNK) worst-case LDS chunk
#define MAXK 112             // per-batch member slot stride (>= PERB)
#define GRID 256             // cooperative grid: 1 block/CU, always co-resident
#define THRNMS 0.3

// f32 sigmoid cascade, bit-matching the numpy f32 reference (validated r3):
//   e = expf(-x) (f64 exp rounded once = correctly-rounded f32 exp)
//   s = 1.0f / (1.0f + e)
__device__ __forceinline__ float sigf(float x) {
    float e = (float)exp(-(double)x);
    return 1.0f / (1.0f + e);
}

__global__ __launch_bounds__(256) void k_fused(
    const float* __restrict__ p,
    float* __restrict__ out,
    unsigned int* __restrict__ key,
    float* __restrict__ score,
    float* __restrict__ box,
    int* __restrict__ meta,
    unsigned long long* __restrict__ ballots,
    unsigned long long* __restrict__ vK,      // (key<<32)|idx, compacted valids
    unsigned int* __restrict__ vrank,
    float4* __restrict__ mbox,
    int* __restrict__ mlab,
    int* __restrict__ mpos,
    unsigned int* __restrict__ bslot)
{
    cg::grid_group grid = cg::this_grid();
    const int tid  = threadIdx.x;
    const int lane = tid & 63;

    __shared__ unsigned long long lk[CLENMAX];   // rank column chunk
    __shared__ unsigned int boff[NBLK];
    __shared__ unsigned int nv_sh;
    __shared__ float mbx[MAXK][4];               // NMS members (arrival order)
    __shared__ int   mlb[MAXK], mps[MAXK];
    __shared__ float rbx[MAXK][4];               // NMS members (sorted order)
    __shared__ int   rlb[MAXK], rps[MAXK], sup[MAXK];

    // ================= P1: decode =================
    if (blockIdx.x < NBLK) {
        int i    = blockIdx.x * 256 + tid;       // box index, exactly N threads
        int j    = i & 1;
        int cell = i >> 1;
        int x = cell % S, y = (cell / S) % S, b = cell / (S * S);
        const float* pc = p + cell * CH;

        float tx = pc[j*4+0], ty = pc[j*4+1], tw = pc[j*4+2], th = pc[j*4+3];
        float craw = pc[8 + j];

        // 20-class argmax split across the even/odd lane pair (same cell):
        // each half does 10 sigmoids; merge keeps first-occurrence semantics.
        int cbase = 10 + j * 10;
        float best = sigf(pc[cbase]); int lab = j * 10;
        #pragma unroll
        for (int c = 1; c < 10; ++c) {
            float v = sigf(pc[cbase + c]);
            if (v > best) { best = v; lab = j * 10 + c; }
        }
        float obest = __shfl_xor(best, 1);
        int   olab  = __shfl_xor(lab, 1);
        float bestA = j ? obest : best;  int labA = j ? olab : lab;   // classes 0-9
        float bestB = j ? best  : obest; int labB = j ? lab  : olab;  // classes 10-19
        int label = (bestB > bestA ? labB : labA) + 1;  // strict >: first max wins

        // f32 box geometry in numpy op order
        float sx = sigf(tx), sy = sigf(ty);
        float cx = (sx + (float)x) / 7.0f;
        float cy = (sy + (float)y) / 7.0f;
        float hw = tw / 2.0f, hh = th / 2.0f;
        float l = cx - hw, t = cy - hh, r = cx + hw, bt = cy + hh;

        float sc = sigf(craw);
        bool valid = sc > 0.5f;

        key[i]   = valid ? __float_as_uint(sc) : 0u;
        score[i] = sc;
        box[i*4+0] = l; box[i*4+1] = t; box[i*4+2] = r; box[i*4+3] = bt;
        meta[i] = (valid ? 0x8000 : 0) | (b << 5) | label;

        unsigned long long vb = __ballot(valid);
        if (lane == 0) ballots[i >> 6] = vb;
    }
    grid.sync();

    // ===== P2: per-block ballot scan (all blocks) + compact (blocks < NBLK) =====
    if ((tid >> 6) == 0) {                       // wave 0: scan 196 ballot words
        unsigned int c = 0;
        if (lane < NBLK) {
            const unsigned long long* bp = ballots + lane * 4;
            c = __popcll(bp[0]) + __popcll(bp[1]) + __popcll(bp[2]) + __popcll(bp[3]);
        }
        unsigned int v = c;
        #pragma unroll
        for (int d = 1; d < 64; d <<= 1) {
            unsigned int o = __shfl_up(v, d);
            if (lane >= d) v += o;
        }
        if (lane < NBLK) boff[lane] = v - c;     // exclusive prefix
        if (lane == 63) nv_sh = v;               // total valids
    }
    __syncthreads();
    const unsigned int nv = nv_sh;

    if (blockIdx.x < NBLK) {
        int i  = blockIdx.x * 256 + tid;
        int wv = tid >> 6;
        int wbase = blockIdx.x * 4;
        unsigned int pre = 0;
        for (int w2 = 0; w2 < wv; ++w2) pre += __popcll(ballots[wbase + w2]);
        unsigned long long myb = ballots[wbase + wv];
        unsigned int wpre = __popcll(myb & ((1ull << lane) - 1ull));
        bool valid = (myb >> lane) & 1ull;
        unsigned int Vexc = boff[blockIdx.x] + pre + wpre;

        if (valid) {
            unsigned int slot = Vexc;
            vK[slot] = ((unsigned long long)key[i] << 32) | (unsigned long long)i;
            vrank[slot] = 0u;
        } else {
            // invalid rank closed-form: (N-1-i) + #valid(idx <= i)
            unsigned int pos = (unsigned int)(N - 1 - i) + Vexc;
            int m = meta[i];
            int b = (m >> 5) & 0x7F;
            out[pos]           = (float)(m >> 5 & 0x7F);
            out[N + pos*4 + 0] = box[i*4+0];
            out[N + pos*4 + 1] = box[i*4+1];
            out[N + pos*4 + 2] = box[i*4+2];
            out[N + pos*4 + 3] = box[i*4+3];
            out[5*N + pos]     = (float)(m & 31);
            out[6*N + pos]     = score[i];
            out[7*N + pos]     = 0.0f;
            (void)b;
        }
    }
    if (blockIdx.x == 0 && tid < NBATCH) bslot[tid] = 0u;
    grid.sync();

    // ================= P3: rank valids (single u64 compare) =================
    {
        unsigned int nrb    = (nv + 255) >> 8;
        unsigned int clen   = (nv + NCHUNK - 1) / NCHUNK;     // <= CLENMAX
        unsigned int ntiles = nrb * NCHUNK;
        for (unsigned int tile = blockIdx.x; tile < ntiles; tile += GRID) {
            unsigned int rb = tile >> 4, ch = tile & (NCHUNK - 1);
            unsigned int base = ch * clen;
            unsigned int len = (base < nv) ? ((nv - base < clen) ? nv - base : clen) : 0;
            __syncthreads();
            for (unsigned int u = tid; u < len; u += 256) lk[u] = vK[base + u];
            __syncthreads();
            unsigned int s = rb * 256 + tid;
            if (s < nv && len) {
                unsigned long long Ki = vK[s];
                unsigned int cnt = 0;
                for (unsigned int u = 0; u < len; ++u)
                    cnt += (lk[u] > Ki) ? 1u : 0u;   // desc key, tie desc idx
                if (cnt) atomicAdd(&vrank[s], cnt);
            }
        }
    }
    grid.sync();

    // ================= P4: scatter valid rows + NMS member lists =================
    for (unsigned int s = blockIdx.x * 256 + tid; s < nv; s += GRID * 256) {
        unsigned long long K = vK[s];
        unsigned int i  = (unsigned int)(K & 0xFFFFFFFFull);
        unsigned int pos = vrank[s];
        int m = meta[i];
        int b = (m >> 5) & 0x7F;
        int label = m & 31;
        float l = box[i*4+0], t = box[i*4+1], r = box[i*4+2], bt = box[i*4+3];

        out[pos]           = (float)b;
        out[N + pos*4 + 0] = l;
        out[N + pos*4 + 1] = t;
        out[N + pos*4 + 2] = r;
        out[N + pos*4 + 3] = bt;
        out[5*N + pos]     = (float)label;
        out[6*N + pos]     = score[i];
        out[7*N + pos]     = 0.0f;               // keep default; P5 sets 1

        unsigned int ms = atomicAdd(&bslot[b], 1u);   // arrival order (unsorted)
        int slot = b * MAXK + (int)ms;
        mbox[slot] = make_float4(l, t, r, bt);
        mlab[slot] = label;
        mpos[slot] = (int)pos;
    }
    grid.sync();

    // ================= P5: greedy NMS, one block per batch =================
    if (blockIdx.x < NBATCH) {
        int b  = blockIdx.x;
        int kb = (int)bslot[b];                  // <= 98 structurally
        if (tid < kb) {
            float4 v = mbox[b * MAXK + tid];
            mbx[tid][0] = v.x; mbx[tid][1] = v.y; mbx[tid][2] = v.z; mbx[tid][3] = v.w;
            mlb[tid] = mlab[b * MAXK + tid];
            mps[tid] = mpos[b * MAXK + tid];
        }
        __syncthreads();
        if (tid < kb) {                          // rank-sort members by global pos
            int pt = mps[tid], rk = 0;
            for (int u = 0; u < kb; ++u) rk += (mps[u] < pt) ? 1 : 0;
            rbx[rk][0] = mbx[tid][0]; rbx[rk][1] = mbx[tid][1];
            rbx[rk][2] = mbx[tid][2]; rbx[rk][3] = mbx[tid][3];
            rlb[rk] = mlb[tid]; rps[rk] = mps[tid]; sup[rk] = 0;
        }
        __syncthreads();

        for (int i = 0; i < kb; ++i) {
            __syncthreads();
            if (sup[i]) continue;                // uniform broadcast read
            float li = rbx[i][0], ti = rbx[i][1], ri = rbx[i][2], bi = rbx[i][3];
            float areai = (ri - li) * (bi - ti);
            int labi = rlb[i];
            int jj = tid;
            if (jj > i && jj < kb && rlb[jj] == labi) {
                float lj = rbx[jj][0], tj = rbx[jj][1], rj = rbx[jj][2], bj = rbx[jj][3];
                float lt0 = fmaxf(li, lj), lt1 = fmaxf(ti, tj);
                float rb0 = fminf(ri, rj), rb1 = fminf(bi, bj);
                float w = rb0 - lt0; if (w < 0.0f) w = 0.0f;
                float h = rb1 - lt1; if (h < 0.0f) h = 0.0f;
                float inter = w * h;
                float areaj = (rj - lj) * (bj - tj);
                float uni = areai + areaj - inter;
                double iou = (double)inter / fmax((double)uni, 1e-9);
                if (iou > THRNMS) sup[jj] = 1;
            }
        }
        __syncthreads();
        if (tid < kb && !sup[tid]) out[7*N + rps[tid]] = 1.0f;
    }
}

extern "C" void kernel_launch(void* const* d_in, const int* in_sizes, int n_in,
                              void* d_out, int out_size, void* d_ws, size_t ws_size,
                              hipStream_t stream)
{
    const float* p = (const float*)d_in[0];
    float* out = (float*)d_out;

    char* w = (char*)d_ws;
    unsigned int* key   = (unsigned int*)w;               w += (size_t)N * 4;
    float* score        = (float*)w;                      w += (size_t)N * 4;
    float* box          = (float*)w;                      w += (size_t)N * 16;
    int* meta           = (int*)w;                        w += (size_t)N * 4;
    unsigned long long* ballots = (unsigned long long*)w; w += (size_t)NWORDS * 8;
    unsigned long long* vK      = (unsigned long long*)w; w += (size_t)N * 8;
    unsigned int* vrank = (unsigned int*)w;               w += (size_t)N * 4;
    float4* mbox        = (float4*)w;                     w += (size_t)NBATCH * MAXK * 16;
    int* mlab           = (int*)w;                        w += (size_t)NBATCH * MAXK * 4;
    int* mpos           = (int*)w;                        w += (size_t)NBATCH * MAXK * 4;
    unsigned int* bslot = (unsigned int*)w;               w += (size_t)NBATCH * 4;

    void* args[] = { (void*)&p, (void*)&out, (void*)&key, (void*)&score,
                     (void*)&box, (void*)&meta, (void*)&ballots, (void*)&vK,
                     (void*)&vrank, (void*)&mbox, (void*)&mlab, (void*)&mpos,
                     (void*)&bslot };
    hipLaunchCooperativeKernel((const void*)k_fused, dim3(GRID), dim3(256),
                               args, 0, stream);
}

// Round 7
// 109.599 us; speedup vs baseline: 1.8326x; 1.8326x over previous
//
#include <hip/hip_runtime.h>
#include <math.h>

#define NBATCH 128
#define S 7
#define NCLS 20
#define CH 30
#define N 12544              // 128*7*7*2
#define PERB 98              // boxes per batch
#define NWORDS 196           // N/64 ballot words
#define NBLK 49              // N/256 blocks over the box domain
#define NCHUNK 16            // rank column chunks
#define CLENMAX 784          // ceil(N/NCHUNK) worst-case LDS chunk
#define MAXK 112             // per-batch member slot stride (>= PERB)
#define THRNMS 0.3

// f32 sigmoid cascade, bit-matching the numpy f32 reference (validated r3-r6):
//   e = expf(-x) (f64 exp rounded once = correctly-rounded f32 exp)
//   s = 1.0f / (1.0f + e)
__device__ __forceinline__ float sigf(float x) {
    float e = (float)exp(-(double)x);
    return 1.0f / (1.0f + e);
}

// ========== K1: decode — records + f32-cascade keys + valid ballots ==========
__global__ __launch_bounds__(256) void k_decode(
    const float* __restrict__ p,
    unsigned int* __restrict__ key,
    float* __restrict__ score,
    float* __restrict__ box,
    int* __restrict__ meta,
    unsigned long long* __restrict__ ballots)
{
    int i    = blockIdx.x * 256 + threadIdx.x;   // exactly N threads
    int lane = threadIdx.x & 63;
    int j    = i & 1;
    int cell = i >> 1;
    int x = cell % S, y = (cell / S) % S, b = cell / (S * S);
    const float* pc = p + cell * CH;

    float tx = pc[j*4+0], ty = pc[j*4+1], tw = pc[j*4+2], th = pc[j*4+3];
    float craw = pc[8 + j];

    // 20-class argmax split across the even/odd lane pair (same cell);
    // merge keeps first-occurrence semantics (validated r6).
    int cbase = 10 + j * 10;
    float best = sigf(pc[cbase]); int lab = j * 10;
    #pragma unroll
    for (int c = 1; c < 10; ++c) {
        float v = sigf(pc[cbase + c]);
        if (v > best) { best = v; lab = j * 10 + c; }
    }
    float obest = __shfl_xor(best, 1);
    int   olab  = __shfl_xor(lab, 1);
    float bestA = j ? obest : best;  int labA = j ? olab : lab;   // classes 0-9
    float bestB = j ? best  : obest; int labB = j ? lab  : olab;  // classes 10-19
    int label = (bestB > bestA ? labB : labA) + 1;   // strict >: first max wins

    // f32 box geometry in numpy op order
    float sx = sigf(tx), sy = sigf(ty);
    float cx = (sx + (float)x) / 7.0f;
    float cy = (sy + (float)y) / 7.0f;
    float hw = tw / 2.0f, hh = th / 2.0f;
    float l = cx - hw, t = cy - hh, r = cx + hw, bt = cy + hh;

    float sc = sigf(craw);
    bool valid = sc > 0.5f;

    key[i]   = valid ? __float_as_uint(sc) : 0u;
    score[i] = sc;
    box[i*4+0] = l; box[i*4+1] = t; box[i*4+2] = r; box[i*4+3] = bt;
    meta[i] = (valid ? 0x8000 : 0) | (b << 5) | label;

    unsigned long long vb = __ballot(valid);
    if (lane == 0) ballots[i >> 6] = vb;
}

// ========== K2: compact valids + emit invalid rows closed-form ==========
// Every block recomputes the 49-entry ballot prefix in wave 0 (no k_scan).
// invalid rank(i) = (N-1-i) + #valid(idx <= i)
__global__ __launch_bounds__(256) void k_compact(
    const unsigned long long* __restrict__ ballots,
    const unsigned int* __restrict__ key,
    const float* __restrict__ score,
    const float* __restrict__ box,
    const int* __restrict__ meta,
    unsigned long long* __restrict__ vK,
    unsigned int* __restrict__ vrank,
    unsigned int* __restrict__ nvalid,
    unsigned int* __restrict__ bslot,
    unsigned int* __restrict__ done,
    float* __restrict__ out)
{
    __shared__ unsigned int boff[NBLK];
    __shared__ unsigned int nv_sh;
    const int tid = threadIdx.x, lane = tid & 63;

    if ((tid >> 6) == 0) {                       // wave 0: scan ballot words
        unsigned int c = 0;
        if (lane < NBLK) {
            const unsigned long long* bp = ballots + lane * 4;
            c = __popcll(bp[0]) + __popcll(bp[1]) + __popcll(bp[2]) + __popcll(bp[3]);
        }
        unsigned int v = c;
        #pragma unroll
        for (int d = 1; d < 64; d <<= 1) {
            unsigned int o = __shfl_up(v, d);
            if (lane >= d) v += o;
        }
        if (lane < NBLK) boff[lane] = v - c;     // exclusive prefix
        if (lane == 63) nv_sh = v;               // total valids
    }
    __syncthreads();

    int i  = blockIdx.x * 256 + tid;
    int wv = tid >> 6;
    int wbase = blockIdx.x * 4;
    unsigned int pre = 0;
    for (int w2 = 0; w2 < wv; ++w2) pre += __popcll(ballots[wbase + w2]);
    unsigned long long myb = ballots[wbase + wv];
    unsigned int wpre = __popcll(myb & ((1ull << lane) - 1ull));
    bool valid = (myb >> lane) & 1ull;
    unsigned int Vexc = boff[blockIdx.x] + pre + wpre;

    if (valid) {
        vK[Vexc] = ((unsigned long long)key[i] << 32) | (unsigned long long)i;
        vrank[Vexc] = 0u;
    } else {
        unsigned int pos = (unsigned int)(N - 1 - i) + Vexc;   // V_inc == V_exc
        int m = meta[i];
        out[pos]           = (float)((m >> 5) & 0x7F);
        out[N + pos*4 + 0] = box[i*4+0];
        out[N + pos*4 + 1] = box[i*4+1];
        out[N + pos*4 + 2] = box[i*4+2];
        out[N + pos*4 + 3] = box[i*4+3];
        out[5*N + pos]     = (float)(m & 31);
        out[6*N + pos]     = score[i];
        out[7*N + pos]     = 0.0f;
    }

    if (blockIdx.x == 0) {
        if (tid < NBATCH) bslot[tid] = 0u;
        if (tid >= 128 && tid < 128 + NBLK) done[tid - 128] = 0u;
        if (tid == 200) nvalid[0] = nv_sh;
    }
}

// ========== K3: rank valids (column-chunked) + last-arriver scatter ==========
// grid (NBLK, NCHUNK). The 16 chunk blocks of row-block rb accumulate
// vrank via device atomics; the 16th arriver (done[rb]) scatters rb's rows.
__global__ __launch_bounds__(256) void k_rankscat(
    const unsigned long long* __restrict__ vK,
    const unsigned int* __restrict__ nvalid_p,
    unsigned int* __restrict__ vrank,
    unsigned int* __restrict__ done,
    const float* __restrict__ score,
    const float* __restrict__ box,
    const int* __restrict__ meta,
    float4* __restrict__ mbox,
    int* __restrict__ mlab,
    int* __restrict__ mpos,
    unsigned int* __restrict__ bslot,
    float* __restrict__ out)
{
    __shared__ unsigned long long lk[CLENMAX];
    __shared__ unsigned int old_sh;
    const int tid = threadIdx.x;
    const unsigned int rb = blockIdx.x, ch = blockIdx.y;
    const unsigned int nv = nvalid_p[0];

    unsigned int clen = (nv + NCHUNK - 1) / NCHUNK;       // <= CLENMAX
    unsigned int base = ch * clen;
    unsigned int len = (base < nv) ? ((nv - base < clen) ? nv - base : clen) : 0;

    for (unsigned int u = tid; u < len; u += 256) lk[u] = vK[base + u];
    __syncthreads();

    unsigned int s = rb * 256 + tid;
    if (s < nv && len) {
        unsigned long long Ki = vK[s];
        unsigned int cnt = 0;
        for (unsigned int u = 0; u < len; ++u)
            cnt += (lk[u] > Ki) ? 1u : 0u;       // desc key, tie desc idx
        if (cnt) atomicAdd(&vrank[s], cnt);
    }
    // __syncthreads implies full vmcnt drain: all this block's atomics landed
    __syncthreads();
    if (tid == 0) {
        __threadfence();
        old_sh = atomicAdd(&done[rb], 1u);
    }
    __syncthreads();

    if (old_sh == NCHUNK - 1) {                  // last arriver: ranks complete
        unsigned int s2 = rb * 256 + tid;
        if (s2 < nv) {
            unsigned int pos = atomicAdd(&vrank[s2], 0u);   // coherent read
            unsigned int i = (unsigned int)(vK[s2] & 0xFFFFFFFFull);
            int m = meta[i];
            int b = (m >> 5) & 0x7F;
            int label = m & 31;
            float l = box[i*4+0], t = box[i*4+1], r = box[i*4+2], bt = box[i*4+3];

            out[pos]           = (float)b;
            out[N + pos*4 + 0] = l;
            out[N + pos*4 + 1] = t;
            out[N + pos*4 + 2] = r;
            out[N + pos*4 + 3] = bt;
            out[5*N + pos]     = (float)label;
            out[6*N + pos]     = score[i];
            out[7*N + pos]     = 0.0f;           // keep default; K4 sets 1

            unsigned int ms = atomicAdd(&bslot[b], 1u);     // arrival order
            int slot = b * MAXK + (int)ms;
            mbox[slot] = make_float4(l, t, r, bt);
            mlab[slot] = label;
            mpos[slot] = (int)pos;
        }
    }
}

// ========== K4: greedy NMS, one block per batch (validated r6 P5) ==========
__global__ __launch_bounds__(128) void k_nms(
    const unsigned int* __restrict__ bslot,
    const float4* __restrict__ mbox,
    const int* __restrict__ mlab,
    const int* __restrict__ mpos,
    float* __restrict__ keepout)
{
    int b = blockIdx.x;
    int tid = threadIdx.x;
    __shared__ float mbx[MAXK][4];               // arrival order
    __shared__ int   mlb[MAXK], mps[MAXK];
    __shared__ float rbx[MAXK][4];               // sorted by global pos
    __shared__ int   rlb[MAXK], rps[MAXK], sup[MAXK];

    int kb = (int)bslot[b];                      // <= 98 structurally
    if (tid < kb) {
        float4 v = mbox[b * MAXK + tid];
        mbx[tid][0] = v.x; mbx[tid][1] = v.y; mbx[tid][2] = v.z; mbx[tid][3] = v.w;
        mlb[tid] = mlab[b * MAXK + tid];
        mps[tid] = mpos[b * MAXK + tid];
    }
    __syncthreads();
    if (tid < kb) {                              // rank-sort members by pos
        int pt = mps[tid], rk = 0;
        for (int u = 0; u < kb; ++u) rk += (mps[u] < pt) ? 1 : 0;
        rbx[rk][0] = mbx[tid][0]; rbx[rk][1] = mbx[tid][1];
        rbx[rk][2] = mbx[tid][2]; rbx[rk][3] = mbx[tid][3];
        rlb[rk] = mlb[tid]; rps[rk] = mps[tid]; sup[rk] = 0;
    }
    __syncthreads();

    for (int i = 0; i < kb; ++i) {
        __syncthreads();
        if (sup[i]) continue;                    // uniform broadcast read
        float li = rbx[i][0], ti = rbx[i][1], ri = rbx[i][2], bi = rbx[i][3];
        float areai = (ri - li) * (bi - ti);
        int labi = rlb[i];
        int jj = tid;
        if (jj > i && jj < kb && rlb[jj] == labi) {
            float lj = rbx[jj][0], tj = rbx[jj][1], rj = rbx[jj][2], bj = rbx[jj][3];
            float lt0 = fmaxf(li, lj), lt1 = fmaxf(ti, tj);
            float rb0 = fminf(ri, rj), rb1 = fminf(bi, bj);
            float w = rb0 - lt0; if (w < 0.0f) w = 0.0f;
            float h = rb1 - lt1; if (h < 0.0f) h = 0.0f;
            float inter = w * h;
            float areaj = (rj - lj) * (bj - tj);
            float uni = areai + areaj - inter;
            double iou = (double)inter / fmax((double)uni, 1e-9);
            if (iou > THRNMS) sup[jj] = 1;
        }
    }
    __syncthreads();
    if (tid < kb && !sup[tid]) keepout[rps[tid]] = 1.0f;
}

extern "C" void kernel_launch(void* const* d_in, const int* in_sizes, int n_in,
                              void* d_out, int out_size, void* d_ws, size_t ws_size,
                              hipStream_t stream)
{
    const float* p = (const float*)d_in[0];
    float* out = (float*)d_out;

    char* w = (char*)d_ws;
    unsigned int* key   = (unsigned int*)w;               w += (size_t)N * 4;
    float* score        = (float*)w;                      w += (size_t)N * 4;
    float* box          = (float*)w;                      w += (size_t)N * 16;
    int* meta           = (int*)w;                        w += (size_t)N * 4;
    unsigned long long* ballots = (unsigned long long*)w; w += (size_t)NWORDS * 8;
    unsigned long long* vK      = (unsigned long long*)w; w += (size_t)N * 8;
    unsigned int* vrank = (unsigned int*)w;               w += (size_t)N * 4;
    float4* mbox        = (float4*)w;                     w += (size_t)NBATCH * MAXK * 16;
    int* mlab           = (int*)w;                        w += (size_t)NBATCH * MAXK * 4;
    int* mpos           = (int*)w;                        w += (size_t)NBATCH * MAXK * 4;
    unsigned int* bslot = (unsigned int*)w;               w += (size_t)NBATCH * 4;
    unsigned int* done  = (unsigned int*)w;               w += (size_t)NBLK * 4;
    unsigned int* nvalid= (unsigned int*)w;               w += 4;

    k_decode  <<<dim3(NBLK),         dim3(256), 0, stream>>>(p, key, score, box, meta, ballots);
    k_compact <<<dim3(NBLK),         dim3(256), 0, stream>>>(ballots, key, score, box, meta,
                                                             vK, vrank, nvalid, bslot, done, out);
    k_rankscat<<<dim3(NBLK, NCHUNK), dim3(256), 0, stream>>>(vK, nvalid, vrank, done,
                                                             score, box, meta,
                                                             mbox, mlab, mpos, bslot, out);
    k_nms     <<<dim3(NBATCH),       dim3(128), 0, stream>>>(bslot, mbox, mlab, mpos,
                                                             out + 7 * N);
}

// Round 8
// 85.426 us; speedup vs baseline: 2.3512x; 1.2830x over previous
//
#include <hip/hip_runtime.h>
#include <math.h>

#define NBATCH 128
#define S 7
#define NCLS 20
#define CH 30
#define N 12544              // 128*7*7*2
#define PERB 98              // boxes per batch
#define NWORDS 196           // N/64 ballot words
#define NBLK 49              // N/256 blocks over the box domain
#define NCHUNK 16            // rank column chunks
#define CLENMAX 784          // ceil(N/NCHUNK) worst-case LDS chunk
#define MAXK 112             // per-batch member capacity (>= PERB)
#define THRNMS 0.3

// f32 sigmoid cascade, bit-matching the numpy f32 reference (validated r3-r7):
//   e = expf(-x) (f64 exp rounded once = correctly-rounded f32 exp)
//   s = 1.0f / (1.0f + e)
__device__ __forceinline__ float sigf(float x) {
    float e = (float)exp(-(double)x);
    return 1.0f / (1.0f + e);
}

// ========== K1: decode — records + f32-cascade keys + valid ballots ==========
__global__ __launch_bounds__(256) void k_decode(
    const float* __restrict__ p,
    unsigned int* __restrict__ key,
    float* __restrict__ score,
    float* __restrict__ box,
    int* __restrict__ meta,
    unsigned long long* __restrict__ ballots)
{
    int i    = blockIdx.x * 256 + threadIdx.x;   // exactly N threads
    int lane = threadIdx.x & 63;
    int j    = i & 1;
    int cell = i >> 1;
    int x = cell % S, y = (cell / S) % S, b = cell / (S * S);
    const float* pc = p + cell * CH;

    float tx = pc[j*4+0], ty = pc[j*4+1], tw = pc[j*4+2], th = pc[j*4+3];
    float craw = pc[8 + j];

    // 20-class argmax split across the even/odd lane pair (same cell);
    // merge keeps first-occurrence semantics (validated r6).
    int cbase = 10 + j * 10;
    float best = sigf(pc[cbase]); int lab = j * 10;
    #pragma unroll
    for (int c = 1; c < 10; ++c) {
        float v = sigf(pc[cbase + c]);
        if (v > best) { best = v; lab = j * 10 + c; }
    }
    float obest = __shfl_xor(best, 1);
    int   olab  = __shfl_xor(lab, 1);
    float bestA = j ? obest : best;  int labA = j ? olab : lab;   // classes 0-9
    float bestB = j ? best  : obest; int labB = j ? lab  : olab;  // classes 10-19
    int label = (bestB > bestA ? labB : labA) + 1;   // strict >: first max wins

    // f32 box geometry in numpy op order
    float sx = sigf(tx), sy = sigf(ty);
    float cx = (sx + (float)x) / 7.0f;
    float cy = (sy + (float)y) / 7.0f;
    float hw = tw / 2.0f, hh = th / 2.0f;
    float l = cx - hw, t = cy - hh, r = cx + hw, bt = cy + hh;

    float sc = sigf(craw);
    bool valid = sc > 0.5f;

    key[i]   = valid ? __float_as_uint(sc) : 0u;
    score[i] = sc;
    box[i*4+0] = l; box[i*4+1] = t; box[i*4+2] = r; box[i*4+3] = bt;
    meta[i] = (valid ? 0x8000 : 0) | (b << 5) | label;

    unsigned long long vb = __ballot(valid);
    if (lane == 0) ballots[i >> 6] = vb;
}

// ========== K2: compact valids + emit invalid rows closed-form ==========
// Every block recomputes the 49-entry ballot prefix in wave 0.
// invalid rank(i) = (N-1-i) + #valid(idx <= i)
__global__ __launch_bounds__(256) void k_compact(
    const unsigned long long* __restrict__ ballots,
    const unsigned int* __restrict__ key,
    const float* __restrict__ score,
    const float* __restrict__ box,
    const int* __restrict__ meta,
    unsigned long long* __restrict__ vK,
    unsigned int* __restrict__ vrank,
    unsigned int* __restrict__ nvalid,
    float* __restrict__ out)
{
    __shared__ unsigned int boff[NBLK];
    __shared__ unsigned int nv_sh;
    const int tid = threadIdx.x, lane = tid & 63;

    if ((tid >> 6) == 0) {                       // wave 0: scan ballot words
        unsigned int c = 0;
        if (lane < NBLK) {
            const unsigned long long* bp = ballots + lane * 4;
            c = __popcll(bp[0]) + __popcll(bp[1]) + __popcll(bp[2]) + __popcll(bp[3]);
        }
        unsigned int v = c;
        #pragma unroll
        for (int d = 1; d < 64; d <<= 1) {
            unsigned int o = __shfl_up(v, d);
            if (lane >= d) v += o;
        }
        if (lane < NBLK) boff[lane] = v - c;     // exclusive prefix
        if (lane == 63) nv_sh = v;               // total valids
    }
    __syncthreads();

    int i  = blockIdx.x * 256 + tid;
    int wv = tid >> 6;
    int wbase = blockIdx.x * 4;
    unsigned int pre = 0;
    for (int w2 = 0; w2 < wv; ++w2) pre += __popcll(ballots[wbase + w2]);
    unsigned long long myb = ballots[wbase + wv];
    unsigned int wpre = __popcll(myb & ((1ull << lane) - 1ull));
    bool valid = (myb >> lane) & 1ull;
    unsigned int Vexc = boff[blockIdx.x] + pre + wpre;

    if (valid) {
        vK[Vexc] = ((unsigned long long)key[i] << 32) | (unsigned long long)i;
        vrank[Vexc] = 0u;
    } else {
        unsigned int pos = (unsigned int)(N - 1 - i) + Vexc;   // V_inc == V_exc
        int m = meta[i];
        out[pos] = (float)((m >> 5) & 0x7F);
        ((float4*)(out + N))[pos] = ((const float4*)box)[i];
        out[5*N + pos] = (float)(m & 31);
        out[6*N + pos] = score[i];
        out[7*N + pos] = 0.0f;
    }

    if (blockIdx.x == 0 && tid == 0) nvalid[0] = nv_sh;
}

// ========== K3: rank valids (column-chunked all-pairs, u64 compare) ==========
// Pure accumulate — no fences, no flags (the fast round-5 structure).
__global__ __launch_bounds__(256) void k_rankv(
    const unsigned long long* __restrict__ vK,
    const unsigned int* __restrict__ nvalid_p,
    unsigned int* __restrict__ vrank)
{
    __shared__ unsigned long long lk[CLENMAX];
    const unsigned int nv = nvalid_p[0];
    if ((unsigned int)(blockIdx.x * 256) >= nv) return;        // block-uniform
    unsigned int clen = (nv + NCHUNK - 1) / NCHUNK;            // <= CLENMAX
    unsigned int base = blockIdx.y * clen;
    if (base >= nv) return;                                    // block-uniform
    unsigned int len = (nv - base < clen) ? nv - base : clen;

    for (unsigned int u = threadIdx.x; u < len; u += 256) lk[u] = vK[base + u];
    __syncthreads();

    unsigned int s = blockIdx.x * 256 + threadIdx.x;
    if (s < nv) {
        unsigned long long Ki = vK[s];
        unsigned int cnt = 0;
        for (unsigned int u = 0; u < len; ++u)
            cnt += (lk[u] > Ki) ? 1u : 0u;        // desc key, tie desc idx
        if (cnt) atomicAdd(&vrank[s], cnt);
    }
}

// ========== K4: scatter + NMS fused, one block per batch ==========
// Members found by scanning vK (batch = idx/98); within-batch sorted order
// is simply descending vK (same comparator as the global sort). Positions
// come from vrank (completed last dispatch). Writes complete output rows
// including keep — no separate scatter kernel.
__global__ __launch_bounds__(256) void k_scatnms(
    const unsigned long long* __restrict__ vK,
    const unsigned int* __restrict__ nvalid_p,
    const unsigned int* __restrict__ vrank,
    const float* __restrict__ score,
    const float* __restrict__ box,
    const int* __restrict__ meta,
    float* __restrict__ out)
{
    const int b   = blockIdx.x;
    const int tid = threadIdx.x;
    __shared__ unsigned long long mK[MAXK];      // members, arrival order
    __shared__ int mslot[MAXK];
    __shared__ unsigned int cnt_sh;
    __shared__ float sbx[MAXK][4];               // members, sorted (vK desc)
    __shared__ int   slb[MAXK], spos[MAXK], sup[MAXK];
    __shared__ float ssc[MAXK];

    if (tid == 0) cnt_sh = 0u;
    __syncthreads();

    const unsigned int nv = nvalid_p[0];
    for (unsigned int s = tid; s < nv; s += 256) {   // coalesced scan
        unsigned long long K = vK[s];
        unsigned int idx = (unsigned int)(K & 0xFFFFFFFFull);
        if ((int)(idx / PERB) == b) {
            unsigned int m = atomicAdd(&cnt_sh, 1u);
            mK[m] = K; mslot[m] = (int)s;
        }
    }
    __syncthreads();
    const int kb = (int)cnt_sh;                  // <= 98 structurally

    if (tid < kb) {                              // rank-sort by vK descending
        unsigned long long Kt = mK[tid];
        int rk = 0;
        for (int u = 0; u < kb; ++u) rk += (mK[u] > Kt) ? 1 : 0;
        unsigned int idx = (unsigned int)(Kt & 0xFFFFFFFFull);
        float4 b4 = ((const float4*)box)[idx];
        sbx[rk][0] = b4.x; sbx[rk][1] = b4.y; sbx[rk][2] = b4.z; sbx[rk][3] = b4.w;
        slb[rk]  = meta[idx] & 31;
        ssc[rk]  = score[idx];
        spos[rk] = (int)vrank[mslot[tid]];
        sup[rk]  = 0;
    }
    __syncthreads();

    for (int i = 0; i < kb; ++i) {               // greedy NMS (proven r6/r7)
        __syncthreads();
        if (sup[i]) continue;                    // uniform broadcast read
        float li = sbx[i][0], ti = sbx[i][1], ri = sbx[i][2], bi = sbx[i][3];
        float areai = (ri - li) * (bi - ti);
        int labi = slb[i];
        int jj = tid;
        if (jj > i && jj < kb && slb[jj] == labi) {
            float lj = sbx[jj][0], tj = sbx[jj][1], rj = sbx[jj][2], bj = sbx[jj][3];
            float lt0 = fmaxf(li, lj), lt1 = fmaxf(ti, tj);
            float rb0 = fminf(ri, rj), rb1 = fminf(bi, bj);
            float w = rb0 - lt0; if (w < 0.0f) w = 0.0f;
            float h = rb1 - lt1; if (h < 0.0f) h = 0.0f;
            float inter = w * h;
            float areaj = (rj - lj) * (bj - tj);
            float uni = areai + areaj - inter;
            double iou = (double)inter / fmax((double)uni, 1e-9);
            if (iou > THRNMS) sup[jj] = 1;
        }
    }
    __syncthreads();

    if (tid < kb) {                              // write complete output rows
        int pos = spos[tid];
        out[pos] = (float)b;
        ((float4*)(out + N))[pos] =
            make_float4(sbx[tid][0], sbx[tid][1], sbx[tid][2], sbx[tid][3]);
        out[5*N + pos] = (float)slb[tid];
        out[6*N + pos] = ssc[tid];
        out[7*N + pos] = sup[tid] ? 0.0f : 1.0f;
    }
}

extern "C" void kernel_launch(void* const* d_in, const int* in_sizes, int n_in,
                              void* d_out, int out_size, void* d_ws, size_t ws_size,
                              hipStream_t stream)
{
    const float* p = (const float*)d_in[0];
    float* out = (float*)d_out;

    char* w = (char*)d_ws;
    float* box          = (float*)w;                      w += (size_t)N * 16;  // 16B-aligned first
    unsigned int* key   = (unsigned int*)w;               w += (size_t)N * 4;
    float* score        = (float*)w;                      w += (size_t)N * 4;
    int* meta           = (int*)w;                        w += (size_t)N * 4;
    unsigned long long* ballots = (unsigned long long*)w; w += (size_t)NWORDS * 8;
    unsigned long long* vK      = (unsigned long long*)w; w += (size_t)N * 8;
    unsigned int* vrank = (unsigned int*)w;               w += (size_t)N * 4;
    unsigned int* nvalid= (unsigned int*)w;               w += 4;

    k_decode <<<dim3(NBLK),         dim3(256), 0, stream>>>(p, key, score, box, meta, ballots);
    k_compact<<<dim3(NBLK),         dim3(256), 0, stream>>>(ballots, key, score, box, meta,
                                                            vK, vrank, nvalid, out);
    k_rankv  <<<dim3(NBLK, NCHUNK), dim3(256), 0, stream>>>(vK, nvalid, vrank);
    k_scatnms<<<dim3(NBATCH),       dim3(256), 0, stream>>>(vK, nvalid, vrank,
                                                            score, box, meta, out);
}